// Round 1
// baseline (1117.883 us; speedup 1.0000x reference)
//
#include <hip/hip_runtime.h>
#include <math.h>

#define NPIX 9216        // 96*96
#define SCALE 0.17677669529663687f

// ---------------------------------------------------------------------------
// Kernel 1: fused Q/KV projection GEMM.  Per batch b:
//   Y[768][9216] = W[768][256] * X[256][9216],  W = [q_weight; kv_weight]
// rows 0..255 -> qbuf, rows 256..767 -> kvbuf.
// BM=BN=128, BK=16, 256 threads, 8x8 microtile (two 4x4 clusters per axis).
// ---------------------------------------------------------------------------
__global__ __launch_bounds__(256) void halo_proj_kernel(
    const float* __restrict__ x,
    const float* __restrict__ qw,
    const float* __restrict__ kvw,
    float* __restrict__ qbuf,
    float* __restrict__ kvbuf)
{
    const int b  = blockIdx.z;
    const int m0 = blockIdx.y * 128;   // output-channel tile base (0..767)
    const int n0 = blockIdx.x * 128;   // pixel tile base
    const int tid = threadIdx.x;
    const int tx = tid & 15;           // column group
    const int ty = tid >> 4;           // row group

    __shared__ float Ws[16][128];      // [k][m]
    __shared__ float Xs[16][128];      // [k][n]

    const float* xb = x + (size_t)b * (256 * NPIX);
    // whole 128-row tile is on one side (m0 is a multiple of 128)
    const float* Wp = (m0 < 256) ? (qw + (size_t)m0 * 256)
                                 : (kvw + (size_t)(m0 - 256) * 256);
    float* ybase = (m0 < 256)
        ? (qbuf + ((size_t)b * 256 + m0) * NPIX)
        : (kvbuf + ((size_t)b * 512 + (m0 - 256)) * NPIX);

    float acc[8][8];
    #pragma unroll
    for (int i = 0; i < 8; ++i)
        #pragma unroll
        for (int j = 0; j < 8; ++j) acc[i][j] = 0.f;

    for (int k0 = 0; k0 < 256; k0 += 16) {
        // --- load W tile: 128 rows x 16 k  (512 float4, 2 per thread)
        #pragma unroll
        for (int t = 0; t < 2; ++t) {
            int idx = tid + t * 256;
            int m  = idx >> 2;
            int kq = (idx & 3) << 2;
            float4 w4 = *(const float4*)(Wp + (size_t)m * 256 + k0 + kq);
            Ws[kq + 0][m] = w4.x;
            Ws[kq + 1][m] = w4.y;
            Ws[kq + 2][m] = w4.z;
            Ws[kq + 3][m] = w4.w;
        }
        // --- load X tile: 16 k-rows x 128 pixels (coalesced float4)
        #pragma unroll
        for (int t = 0; t < 2; ++t) {
            int idx = tid + t * 256;
            int kk = idx >> 5;
            int nn = (idx & 31) << 2;
            float4 x4 = *(const float4*)(xb + (size_t)(k0 + kk) * NPIX + n0 + nn);
            *(float4*)&Xs[kk][nn] = x4;
        }
        __syncthreads();

        #pragma unroll
        for (int k = 0; k < 16; ++k) {
            float a[8], bb[8];
            #pragma unroll
            for (int i = 0; i < 4; ++i) {
                a[i]     = Ws[k][ty * 4 + i];
                a[4 + i] = Ws[k][64 + ty * 4 + i];
            }
            #pragma unroll
            for (int j = 0; j < 4; ++j) {
                bb[j]     = Xs[k][tx * 4 + j];
                bb[4 + j] = Xs[k][64 + tx * 4 + j];
            }
            #pragma unroll
            for (int i = 0; i < 8; ++i)
                #pragma unroll
                for (int j = 0; j < 8; ++j)
                    acc[i][j] += a[i] * bb[j];
        }
        __syncthreads();
    }

    // --- epilogue: 16 float4 stores per thread
    #pragma unroll
    for (int ih = 0; ih < 2; ++ih) {
        #pragma unroll
        for (int i = 0; i < 4; ++i) {
            int r = ih * 64 + ty * 4 + i;
            float* dst = ybase + (size_t)r * NPIX + n0;
            #pragma unroll
            for (int jh = 0; jh < 2; ++jh) {
                float4 v = make_float4(acc[ih * 4 + i][jh * 4 + 0],
                                       acc[ih * 4 + i][jh * 4 + 1],
                                       acc[ih * 4 + i][jh * 4 + 2],
                                       acc[ih * 4 + i][jh * 4 + 3]);
                *(float4*)(dst + jh * 64 + tx * 4) = v;
            }
        }
    }
}

// ---------------------------------------------------------------------------
// Kernel 2: halo attention.  One block per (bh in 64, nb in 144).
// 256 threads = 4 waves.  Lane owns qpos = wave*16 + (lane&15);
// lane group (lane>>4) covers 49 of the 196 keys.  Softmax reduced across
// the 4 owning lanes with __shfl_xor(16/32).  v reuses k's LDS after logits.
// ---------------------------------------------------------------------------
__global__ __launch_bounds__(256) void halo_attn_kernel(
    const float* __restrict__ qbuf,
    const float* __restrict__ kvbuf,
    const float* __restrict__ hrel,
    const float* __restrict__ wrel,
    float* __restrict__ out)
{
    const int nbid = blockIdx.x;          // 0..143
    const int bh   = blockIdx.y;          // 0..63
    const int b    = bh >> 3, head = bh & 7;
    const int hb   = nbid / 12, wb = nbid % 12;
    const int tid  = threadIdx.x;
    const int lane = tid & 63, wave = tid >> 6;

    __shared__ float q_s[64][36];         // [qpos][d], padded
    __shared__ float k_s[196][36];        // [kpos][d], padded; reused for v
    __shared__ float relh_s[64][14];
    __shared__ float relw_s[64][14];

    const float* qptr = qbuf + ((size_t)(b * 256 + head * 32)) * NPIX;
    const float* kptr = kvbuf + ((size_t)(b * 512 + head * 64)) * NPIX;
    const float* vptr = kptr + (size_t)32 * NPIX;

    const int r0 = hb * 8, c0 = wb * 8;

    // ---- stage q (64 x 32)
    for (int e = tid; e < 2048; e += 256) {
        int d = e >> 6, qp = e & 63;
        q_s[qp][d] = qptr[(size_t)d * NPIX + (r0 + (qp >> 3)) * 96 + c0 + (qp & 7)];
    }
    // ---- stage k (196 x 32) with halo-3 zero padding
    for (int e = tid; e < 6272; e += 256) {
        int d = e / 196, kp = e % 196;
        int a = kp / 14, b2 = kp % 14;
        int gr = r0 + a - 3, gc = c0 + b2 - 3;
        bool ok = ((unsigned)gr < 96u) && ((unsigned)gc < 96u);
        k_s[kp][d] = ok ? kptr[(size_t)d * NPIX + gr * 96 + gc] : 0.0f;
    }
    __syncthreads();

    // ---- relative-position logits: relh[qp][a] = q[qp]·hrel[13+a-h],
    //      relw[qp][b2] = q[qp]·wrel[13+b2-w]   (h=qp>>3, w=qp&7)
    for (int e = tid; e < 1792; e += 256) {
        int half = (e >= 896) ? 1 : 0;
        int rem  = e - half * 896;
        int qp   = rem / 14, idx = rem % 14;
        int row  = 13 + idx - (half ? (qp & 7) : (qp >> 3));
        const float* rl = (half ? wrel : hrel) + (size_t)row * 32;
        float s = 0.f;
        #pragma unroll
        for (int d = 0; d < 32; ++d) s += q_s[qp][d] * rl[d];
        if (half) relw_s[qp][idx] = s; else relh_s[qp][idx] = s;
    }
    __syncthreads();

    const int qp = (wave << 4) | (lane & 15);
    const int kb = (lane >> 4) * 49;

    float qreg[32];
    #pragma unroll
    for (int d = 0; d < 32; ++d) qreg[d] = q_s[qp][d];

    // ---- logits for this lane's 49 keys
    float lg[49];
    #pragma unroll
    for (int i = 0; i < 49; ++i) {
        int kp = kb + i;
        float s = 0.f;
        #pragma unroll
        for (int d = 0; d < 32; ++d) s += qreg[d] * k_s[kp][d];
        lg[i] = s * SCALE + relh_s[qp][kp / 14] + relw_s[qp][kp % 14];
    }

    // ---- softmax across 196 (4 lanes share qp: xor 16, 32)
    float mx = lg[0];
    #pragma unroll
    for (int i = 1; i < 49; ++i) mx = fmaxf(mx, lg[i]);
    mx = fmaxf(mx, __shfl_xor(mx, 16));
    mx = fmaxf(mx, __shfl_xor(mx, 32));
    float sm = 0.f;
    #pragma unroll
    for (int i = 0; i < 49; ++i) { lg[i] = __expf(lg[i] - mx); sm += lg[i]; }
    sm += __shfl_xor(sm, 16);
    sm += __shfl_xor(sm, 32);
    const float rs = 1.0f / sm;

    __syncthreads();   // everyone done with k_s
    // ---- stage v into k_s
    for (int e = tid; e < 6272; e += 256) {
        int d = e / 196, kp = e % 196;
        int a = kp / 14, b2 = kp % 14;
        int gr = r0 + a - 3, gc = c0 + b2 - 3;
        bool ok = ((unsigned)gr < 96u) && ((unsigned)gc < 96u);
        k_s[kp][d] = ok ? vptr[(size_t)d * NPIX + gr * 96 + gc] : 0.0f;
    }
    __syncthreads();

    // ---- PV: partial over this lane's 49 keys, then cross-lane reduce
    float acc[32];
    #pragma unroll
    for (int d = 0; d < 32; ++d) acc[d] = 0.f;
    #pragma unroll
    for (int i = 0; i < 49; ++i) {
        float p = lg[i];
        #pragma unroll
        for (int d = 0; d < 32; ++d) acc[d] += p * k_s[kb + i][d];
    }
    #pragma unroll
    for (int d = 0; d < 32; ++d) {
        acc[d] += __shfl_xor(acc[d], 16);
        acc[d] += __shfl_xor(acc[d], 32);
    }

    __syncthreads();   // PV done everywhere; q_s free for reuse
    float* out_t = &q_s[0][0];       // [32][64]: out_t[d*64+qp]
    if (lane < 16) {
        #pragma unroll
        for (int d = 0; d < 32; ++d) out_t[d * 64 + qp] = acc[d] * rs;
    }
    __syncthreads();

    float* ob = out + ((size_t)(b * 256 + head * 32)) * NPIX;
    for (int e = tid; e < 2048; e += 256) {
        int d = e >> 6, qp2 = e & 63;
        ob[(size_t)d * NPIX + (r0 + (qp2 >> 3)) * 96 + c0 + (qp2 & 7)] =
            out_t[d * 64 + qp2];
    }
}

extern "C" void kernel_launch(void* const* d_in, const int* in_sizes, int n_in,
                              void* d_out, int out_size, void* d_ws, size_t ws_size,
                              hipStream_t stream) {
    const float* x    = (const float*)d_in[0];
    const float* qw   = (const float*)d_in[1];
    const float* kvw  = (const float*)d_in[2];
    const float* hrel = (const float*)d_in[3];
    const float* wrel = (const float*)d_in[4];
    float* out = (float*)d_out;

    // workspace: kv (8*512*9216 f32) then q (8*256*9216 f32) = 216 MiB
    float* kvbuf = (float*)d_ws;
    float* qbuf  = kvbuf + (size_t)8 * 512 * NPIX;

    halo_proj_kernel<<<dim3(72, 6, 8), 256, 0, stream>>>(x, qw, kvw, qbuf, kvbuf);
    halo_attn_kernel<<<dim3(144, 64), 256, 0, stream>>>(qbuf, kvbuf, hrel, wrel, out);
}

// Round 3
// 349.251 us; speedup vs baseline: 3.2008x; 3.2008x over previous
//
#include <hip/hip_runtime.h>
#include <math.h>

#define NPIX 9216        // 96*96
#define SCALE 0.17677669529663687f

typedef __attribute__((ext_vector_type(8))) short bh8;   // 8 x bf16 (4 VGPRs)
typedef __attribute__((ext_vector_type(4))) float f4;    // MFMA C/D

__device__ __forceinline__ unsigned short f2bf(float f) {
    unsigned u = __float_as_uint(f);
    u += 0x7fff + ((u >> 16) & 1);          // RNE
    return (unsigned short)(u >> 16);
}
__device__ __forceinline__ void gload_lds16(const void* g, void* l) {
    __builtin_amdgcn_global_load_lds(
        (const __attribute__((address_space(1))) unsigned int*)g,
        (__attribute__((address_space(3))) unsigned int*)l, 16, 0, 0);
}

// ---------------------------------------------------------------------------
// Kernel 0: W (q;kv) fp32 -> bf16, concatenated [768][256]
// ---------------------------------------------------------------------------
__global__ void wconv_kernel(const float* __restrict__ qw, const float* __restrict__ kvw,
                             unsigned short* __restrict__ Wb) {
    int row = blockIdx.x, col = threadIdx.x;
    float v = (row < 256) ? qw[row * 256 + col] : kvw[(row - 256) * 256 + col];
    Wb[row * 256 + col] = f2bf(v);
}

// ---------------------------------------------------------------------------
// Kernel 1: x[b][256][9216] fp32 -> xt[b][9216][256] bf16 (transpose+convert)
// ---------------------------------------------------------------------------
__global__ __launch_bounds__(256) void xtrans_kernel(const float* __restrict__ x,
                                                     unsigned short* __restrict__ xt) {
    int b = blockIdx.z;
    int p0 = blockIdx.x * 128, c0 = blockIdx.y * 128;
    int tid = threadIdx.x;
    __shared__ __align__(16) unsigned short ts[128 * 136];   // [pix][ch], pitch 136
    const float* xb = x + (size_t)b * 256 * NPIX;
    #pragma unroll
    for (int it = 0; it < 16; ++it) {
        int e = it * 256 + tid;
        int ch = e >> 5, p4 = (e & 31) * 4;
        float4 v = *(const float4*)(xb + (size_t)(c0 + ch) * NPIX + p0 + p4);
        ts[(p4 + 0) * 136 + ch] = f2bf(v.x);
        ts[(p4 + 1) * 136 + ch] = f2bf(v.y);
        ts[(p4 + 2) * 136 + ch] = f2bf(v.z);
        ts[(p4 + 3) * 136 + ch] = f2bf(v.w);
    }
    __syncthreads();
    unsigned short* xtb = xt + (size_t)b * NPIX * 256;
    #pragma unroll
    for (int it = 0; it < 8; ++it) {
        int e = it * 256 + tid;
        int p = e >> 4, ck = (e & 15) * 8;
        *(int4*)(xtb + (size_t)(p0 + p) * 256 + c0 + ck) = *(const int4*)&ts[p * 136 + ck];
    }
}

// ---------------------------------------------------------------------------
// Kernel 2: projection GEMM, bf16 MFMA.
//   D[pix][outch] = sum_k xt[pix][k] * Wb[outch][k]
// Output scattered into q: [bh][pix][32] / kv: [bh][pix][64] bf16 (pixel-major).
// ---------------------------------------------------------------------------
__global__ __launch_bounds__(256) void proj_kernel(const unsigned short* __restrict__ xt,
                                                   const unsigned short* __restrict__ Wb,
                                                   unsigned short* __restrict__ qb,
                                                   unsigned short* __restrict__ kvb) {
    int b = blockIdx.z;
    int m0 = blockIdx.x * 128;   // pix
    int n0 = blockIdx.y * 128;   // out-ch
    int tid = threadIdx.x, lane = tid & 63, wave = tid >> 6;
    __shared__ __align__(16) char smem[32768];
    char* As = smem;             // [128 pix][64 k] bf16, rows 128 B
    char* Bs = smem + 16384;     // [128 ch ][64 k] bf16
    const unsigned short* xtb = xt + (size_t)b * NPIX * 256;

    f4 acc[4][4] = {};
    int wm = (wave & 1) * 64, wn = (wave >> 1) * 64;

    for (int k0 = 0; k0 < 256; k0 += 64) {
        __syncthreads();
        #pragma unroll
        for (int i = 0; i < 4; ++i) {
            int c = wave * 4 + i;   // chunk: 8 rows x 128B = 1 KB
            gload_lds16(xtb + (size_t)(m0 + c * 8 + (lane >> 3)) * 256 + k0 + (lane & 7) * 8,
                        As + c * 1024);
            gload_lds16(Wb + (size_t)(n0 + c * 8 + (lane >> 3)) * 256 + k0 + (lane & 7) * 8,
                        Bs + c * 1024);
        }
        __syncthreads();
        #pragma unroll
        for (int ks = 0; ks < 2; ++ks) {
            bh8 af[4], bf[4];
            #pragma unroll
            for (int i = 0; i < 4; ++i)
                af[i] = *(const bh8*)(As + (wm + i * 16 + (lane & 15)) * 128 + ks * 64 + (lane >> 4) * 16);
            #pragma unroll
            for (int j = 0; j < 4; ++j)
                bf[j] = *(const bh8*)(Bs + (wn + j * 16 + (lane & 15)) * 128 + ks * 64 + (lane >> 4) * 16);
            #pragma unroll
            for (int i = 0; i < 4; ++i)
                #pragma unroll
                for (int j = 0; j < 4; ++j)
                    acc[i][j] = __builtin_amdgcn_mfma_f32_16x16x32_bf16(af[i], bf[j], acc[i][j], 0, 0, 0);
        }
    }

    bool isQ = (n0 < 256);
    int q4 = (lane >> 4) * 4;
    #pragma unroll
    for (int i = 0; i < 4; ++i) {
        #pragma unroll
        for (int j = 0; j < 4; ++j) {
            int ch = n0 + wn + j * 16 + (lane & 15);
            #pragma unroll
            for (int r = 0; r < 4; ++r) {
                int pix = m0 + wm + i * 16 + q4 + r;
                unsigned short v = f2bf(acc[i][j][r]);
                if (isQ) {
                    int head = ch >> 5, d = ch & 31;
                    qb[((size_t)(b * 8 + head) * NPIX + pix) * 32 + d] = v;
                } else {
                    int c = ch - 256, head = c >> 6, dv = c & 63;
                    kvb[((size_t)(b * 8 + head) * NPIX + pix) * 64 + dv] = v;
                }
            }
        }
    }
}

// ---------------------------------------------------------------------------
// Kernel 3: halo attention, bf16 MFMA. One block per (bh 64, nb 144), 4 waves.
// Wave owns a 16-qpos strip. QK^T: 13 MFMAs; rel: 4 MFMAs; PV: 14 MFMAs.
// LDS (48896 B -> 3 blocks/CU):
//   [0,17920)      Vs[224][40] bf16                 (all phases)
//   [17920,34560)  Ks[208][40] bf16                 (phases 0-1)
//   [34560,39680)  Qs[64][40]  bf16                 (phase 0; dead after aq)
//   [34560,41728)  Rh[64][28]  fp32  (overlays Qs; written after sync S2)
//   [41728,48896)  Rw[64][28]  fp32
//   [17920,47616)  Ps 4x[16][232] bf16              (phase 2, overlays Ks/Rh/Rw)
// ---------------------------------------------------------------------------
__global__ __launch_bounds__(256) void attn_kernel(const unsigned short* __restrict__ qbuf,
                                                   const unsigned short* __restrict__ kvbuf,
                                                   const float* __restrict__ hrel,
                                                   const float* __restrict__ wrel,
                                                   float* __restrict__ out) {
    int nbid = blockIdx.x, bh = blockIdx.y;
    int b = bh >> 3, head = bh & 7;
    int hb = nbid / 12, wblk = nbid % 12;
    int r0 = hb * 8, c0 = wblk * 8;
    int tid = threadIdx.x, lane = tid & 63, wave = tid >> 6;

    __shared__ __align__(16) char smem[48896];
    unsigned short* Vs = (unsigned short*)smem;             // [224][40]
    unsigned short* Ks = (unsigned short*)(smem + 17920);   // [208][40]
    unsigned short* Qs = (unsigned short*)(smem + 34560);   // [64][40]
    float*          Rh = (float*)(smem + 34560);            // [64][28] fp32
    float*          Rw = (float*)(smem + 41728);            // [64][28] fp32
    unsigned short* Ps = (unsigned short*)(smem + 17920 + wave * 7424);  // [16][232]

    const unsigned short* qb  = qbuf  + (size_t)bh * NPIX * 32;
    const unsigned short* kvb = kvbuf + (size_t)bh * NPIX * 64;

    {   // Q stage: 64 rows x 64 B (one int4 per thread)
        int qp = tid >> 2, part = tid & 3;
        int pix = (r0 + (qp >> 3)) * 96 + c0 + (qp & 7);
        *(int4*)&Qs[qp * 40 + part * 8] = *(const int4*)&qb[(size_t)pix * 32 + part * 8];
    }
    for (int e = tid; e < 832; e += 256) {   // K: 208 rows x 64 B, halo-zeroed
        int kp = e >> 2, part = e & 3;
        int4 v = {0, 0, 0, 0};
        if (kp < 196) {
            int a = kp / 14, b2 = kp - a * 14;
            int gr = r0 + a - 3, gc = c0 + b2 - 3;
            if ((unsigned)gr < 96u && (unsigned)gc < 96u)
                v = *(const int4*)&kvb[(size_t)(gr * 96 + gc) * 64 + part * 8];
        }
        *(int4*)&Ks[kp * 40 + part * 8] = v;
    }
    for (int e = tid; e < 896; e += 256) {   // V: 224 rows x 64 B
        int kp = e >> 2, part = e & 3;
        int4 v = {0, 0, 0, 0};
        if (kp < 196) {
            int a = kp / 14, b2 = kp - a * 14;
            int gr = r0 + a - 3, gc = c0 + b2 - 3;
            if ((unsigned)gr < 96u && (unsigned)gc < 96u)
                v = *(const int4*)&kvb[(size_t)(gr * 96 + gc) * 64 + 32 + part * 8];
        }
        *(int4*)&Vs[kp * 40 + part * 8] = v;
    }
    __syncthreads();                               // S1

    int m0 = wave * 16;
    int ll = lane & 15, lq = lane >> 4;
    f4 zero4 = {0.f, 0.f, 0.f, 0.f};

    bh8 aq = *(const bh8*)&Qs[(m0 + ll) * 40 + lq * 8];

    __syncthreads();                               // S2: Qs dead -> Rh may overlay

    // ---- rel logits: Rh[qp][r] = Q[qp].hrel[r]  (fp32, 4 MFMAs/wave)
    #pragma unroll
    for (int t = 0; t < 2; ++t) {
        int r = t * 16 + ll;
        bh8 hb8 = {0, 0, 0, 0, 0, 0, 0, 0};
        bh8 wb8 = {0, 0, 0, 0, 0, 0, 0, 0};
        if (r < 27) {
            const float* hp = hrel + r * 32 + lq * 8;
            const float* wp = wrel + r * 32 + lq * 8;
            #pragma unroll
            for (int j = 0; j < 8; ++j) {
                hb8[j] = (short)f2bf(hp[j]);
                wb8[j] = (short)f2bf(wp[j]);
            }
        }
        f4 ch4 = __builtin_amdgcn_mfma_f32_16x16x32_bf16(aq, hb8, zero4, 0, 0, 0);
        f4 cw4 = __builtin_amdgcn_mfma_f32_16x16x32_bf16(aq, wb8, zero4, 0, 0, 0);
        if (r < 27) {
            #pragma unroll
            for (int rr = 0; rr < 4; ++rr) {
                int row = m0 + lq * 4 + rr;
                Rh[row * 28 + r] = ch4[rr];
                Rw[row * 28 + r] = cw4[rr];
            }
        }
    }

    // ---- S = Q K^T (13 MFMAs)
    f4 S[13];
    #pragma unroll
    for (int t = 0; t < 13; ++t) {
        bh8 bk = *(const bh8*)&Ks[(t * 16 + ll) * 40 + lq * 8];
        S[t] = __builtin_amdgcn_mfma_f32_16x16x32_bf16(aq, bk, zero4, 0, 0, 0);
    }

    // ---- logits = S*SCALE + relh[13+a-h] + relw[13+b2-w]; mask kp>=196
    float mx[4] = {-3e30f, -3e30f, -3e30f, -3e30f};
    #pragma unroll
    for (int t = 0; t < 13; ++t) {
        int kp = t * 16 + ll;
        bool valid = kp < 196;
        int a = kp / 14, b2 = kp - a * 14;
        #pragma unroll
        for (int rr = 0; rr < 4; ++rr) {
            int row = m0 + lq * 4 + rr;
            int ha = 13 + a - (row >> 3);     // in [6,27], Rh row has 28 cols
            int wa = 13 + b2 - (row & 7);     // in [6,26]
            float lgv = valid
                ? S[t][rr] * SCALE + Rh[row * 28 + ha] + Rw[row * 28 + wa]
                : -3e30f;
            S[t][rr] = lgv;
            mx[rr] = fmaxf(mx[rr], lgv);
        }
    }
    #pragma unroll
    for (int rr = 0; rr < 4; ++rr) {
        mx[rr] = fmaxf(mx[rr], __shfl_xor(mx[rr], 1));
        mx[rr] = fmaxf(mx[rr], __shfl_xor(mx[rr], 2));
        mx[rr] = fmaxf(mx[rr], __shfl_xor(mx[rr], 4));
        mx[rr] = fmaxf(mx[rr], __shfl_xor(mx[rr], 8));
    }
    float sm4[4] = {0.f, 0.f, 0.f, 0.f};
    #pragma unroll
    for (int t = 0; t < 13; ++t)
        #pragma unroll
        for (int rr = 0; rr < 4; ++rr) {
            float p = __expf(S[t][rr] - mx[rr]);
            S[t][rr] = p;
            sm4[rr] += p;
        }
    #pragma unroll
    for (int rr = 0; rr < 4; ++rr) {
        sm4[rr] += __shfl_xor(sm4[rr], 1);
        sm4[rr] += __shfl_xor(sm4[rr], 2);
        sm4[rr] += __shfl_xor(sm4[rr], 4);
        sm4[rr] += __shfl_xor(sm4[rr], 8);
    }

    __syncthreads();   // S3: all waves done with Ks/Rh/Rw before Ps overlay

    // ---- P -> LDS in A-operand layout (wave-private strip)
    #pragma unroll
    for (int t = 0; t < 13; ++t) {
        int col = t * 16 + ll;
        #pragma unroll
        for (int rr = 0; rr < 4; ++rr)
            Ps[(lq * 4 + rr) * 232 + col] = f2bf(S[t][rr]);
    }
    if (lane < 32) {   // zero pad cols 208..223
        int rowl = lane & 15, half = lane >> 4;
        *(int4*)&Ps[rowl * 232 + 208 + half * 8] = (int4){0, 0, 0, 0};
    }

    // ---- O = P V (7 k-steps x 2 d-tiles)
    f4 O[2] = {zero4, zero4};
    #pragma unroll
    for (int kt = 0; kt < 7; ++kt) {
        bh8 ap = *(const bh8*)&Ps[ll * 232 + kt * 32 + lq * 8];
        #pragma unroll
        for (int nt = 0; nt < 2; ++nt) {
            int dcol = nt * 16 + ll, kpb = kt * 32 + lq * 8;
            bh8 bv;
            #pragma unroll
            for (int j = 0; j < 8; ++j) bv[j] = (short)Vs[(kpb + j) * 40 + dcol];
            O[nt] = __builtin_amdgcn_mfma_f32_16x16x32_bf16(ap, bv, O[nt], 0, 0, 0);
        }
    }

    // ---- epilogue: divide by row-sum, scatter fp32
    float* ob = out + (size_t)(b * 256 + head * 32) * NPIX;
    #pragma unroll
    for (int rr = 0; rr < 4; ++rr) {
        int qp = m0 + lq * 4 + rr;
        int pix = (r0 + (qp >> 3)) * 96 + c0 + (qp & 7);
        float inv = 1.0f / sm4[rr];
        #pragma unroll
        for (int nt = 0; nt < 2; ++nt) {
            int d = nt * 16 + ll;
            ob[(size_t)d * NPIX + pix] = O[nt][rr] * inv;
        }
    }
}

extern "C" void kernel_launch(void* const* d_in, const int* in_sizes, int n_in,
                              void* d_out, int out_size, void* d_ws, size_t ws_size,
                              hipStream_t stream) {
    const float* x    = (const float*)d_in[0];
    const float* qw   = (const float*)d_in[1];
    const float* kvw  = (const float*)d_in[2];
    const float* hrel = (const float*)d_in[3];
    const float* wrel = (const float*)d_in[4];
    float* out = (float*)d_out;

    char* ws = (char*)d_ws;
    unsigned short* xt    = (unsigned short*)ws;                 // 37,748,736 B
    unsigned short* Wb    = (unsigned short*)(ws + 37748736);    //    393,216 B
    unsigned short* qbuf  = (unsigned short*)(ws + 38141952);    // 37,748,736 B
    unsigned short* kvbuf = (unsigned short*)(ws + 75890688);    // 75,497,472 B

    wconv_kernel<<<dim3(768), 256, 0, stream>>>(qw, kvw, Wb);
    xtrans_kernel<<<dim3(72, 2, 8), 256, 0, stream>>>(x, xt);
    proj_kernel<<<dim3(72, 6, 8), 256, 0, stream>>>(xt, Wb, qbuf, kvbuf);
    attn_kernel<<<dim3(144, 64), 256, 0, stream>>>(qbuf, kvbuf, hrel, wrel, out);
}

// Round 4
// 279.711 us; speedup vs baseline: 3.9966x; 1.2486x over previous
//
#include <hip/hip_runtime.h>
#include <math.h>

#define NPIX 9216        // 96*96
#define SCALE 0.17677669529663687f
#define LOG2E 1.4426950408889634f

typedef __attribute__((ext_vector_type(8))) short bh8;   // 8 x bf16 (4 VGPRs)
typedef __attribute__((ext_vector_type(4))) float f4;    // MFMA C/D

__device__ __forceinline__ unsigned short f2bf(float f) {
    unsigned u = __float_as_uint(f);
    u += 0x7fff + ((u >> 16) & 1);          // RNE
    return (unsigned short)(u >> 16);
}
__device__ __forceinline__ void gload_lds16(const void* g, void* l) {
    __builtin_amdgcn_global_load_lds(
        (const __attribute__((address_space(1))) unsigned int*)g,
        (__attribute__((address_space(3))) unsigned int*)l, 16, 0, 0);
}

// ---------------------------------------------------------------------------
// Kernel 0: W (q;kv) fp32 -> bf16 [768][256]; blocks 768+: hrel/wrel fp32 ->
// bf16 relb[2][32][32], pre-scaled by LOG2E, rows >=27 zeroed.
// ---------------------------------------------------------------------------
__global__ void wconv_kernel(const float* __restrict__ qw, const float* __restrict__ kvw,
                             const float* __restrict__ hrel, const float* __restrict__ wrel,
                             unsigned short* __restrict__ Wb,
                             unsigned short* __restrict__ relb) {
    int bid = blockIdx.x, tid = threadIdx.x;
    if (bid < 768) {
        float v = (bid < 256) ? qw[bid * 256 + tid] : kvw[(bid - 256) * 256 + tid];
        Wb[bid * 256 + tid] = f2bf(v);
    } else {
        int e = (bid - 768) * 256 + tid;      // [0, 2048)
        int half = e >> 10, r = (e >> 5) & 31, d = e & 31;
        float v = 0.0f;
        if (r < 27) v = (half ? wrel : hrel)[r * 32 + d] * LOG2E;
        relb[half * 1024 + r * 32 + d] = f2bf(v);
    }
}

// ---------------------------------------------------------------------------
// Kernel 1: x[b][256][9216] fp32 -> xt[b][9216][256] bf16 (transpose+convert)
// ---------------------------------------------------------------------------
__global__ __launch_bounds__(256) void xtrans_kernel(const float* __restrict__ x,
                                                     unsigned short* __restrict__ xt) {
    int b = blockIdx.z;
    int p0 = blockIdx.x * 128, c0 = blockIdx.y * 128;
    int tid = threadIdx.x;
    __shared__ __align__(16) unsigned short ts[128 * 136];   // [pix][ch], pitch 136
    const float* xb = x + (size_t)b * 256 * NPIX;
    #pragma unroll
    for (int it = 0; it < 16; ++it) {
        int e = it * 256 + tid;
        int ch = e >> 5, p4 = (e & 31) * 4;
        float4 v = *(const float4*)(xb + (size_t)(c0 + ch) * NPIX + p0 + p4);
        ts[(p4 + 0) * 136 + ch] = f2bf(v.x);
        ts[(p4 + 1) * 136 + ch] = f2bf(v.y);
        ts[(p4 + 2) * 136 + ch] = f2bf(v.z);
        ts[(p4 + 3) * 136 + ch] = f2bf(v.w);
    }
    __syncthreads();
    unsigned short* xtb = xt + (size_t)b * NPIX * 256;
    #pragma unroll
    for (int it = 0; it < 8; ++it) {
        int e = it * 256 + tid;
        int p = e >> 4, ck = (e & 15) * 8;
        *(int4*)(xtb + (size_t)(p0 + p) * 256 + c0 + ck) = *(const int4*)&ts[p * 136 + ck];
    }
}

// ---------------------------------------------------------------------------
// Kernel 2: projection GEMM, bf16 MFMA (unchanged from round 3).
// ---------------------------------------------------------------------------
__global__ __launch_bounds__(256) void proj_kernel(const unsigned short* __restrict__ xt,
                                                   const unsigned short* __restrict__ Wb,
                                                   unsigned short* __restrict__ qb,
                                                   unsigned short* __restrict__ kvb) {
    int b = blockIdx.z;
    int m0 = blockIdx.x * 128;   // pix
    int n0 = blockIdx.y * 128;   // out-ch
    int tid = threadIdx.x, lane = tid & 63, wave = tid >> 6;
    __shared__ __align__(16) char smem[32768];
    char* As = smem;             // [128 pix][64 k] bf16, rows 128 B
    char* Bs = smem + 16384;     // [128 ch ][64 k] bf16
    const unsigned short* xtb = xt + (size_t)b * NPIX * 256;

    f4 acc[4][4] = {};
    int wm = (wave & 1) * 64, wn = (wave >> 1) * 64;

    for (int k0 = 0; k0 < 256; k0 += 64) {
        __syncthreads();
        #pragma unroll
        for (int i = 0; i < 4; ++i) {
            int c = wave * 4 + i;   // chunk: 8 rows x 128B = 1 KB
            gload_lds16(xtb + (size_t)(m0 + c * 8 + (lane >> 3)) * 256 + k0 + (lane & 7) * 8,
                        As + c * 1024);
            gload_lds16(Wb + (size_t)(n0 + c * 8 + (lane >> 3)) * 256 + k0 + (lane & 7) * 8,
                        Bs + c * 1024);
        }
        __syncthreads();
        #pragma unroll
        for (int ks = 0; ks < 2; ++ks) {
            bh8 af[4], bf[4];
            #pragma unroll
            for (int i = 0; i < 4; ++i)
                af[i] = *(const bh8*)(As + (wm + i * 16 + (lane & 15)) * 128 + ks * 64 + (lane >> 4) * 16);
            #pragma unroll
            for (int j = 0; j < 4; ++j)
                bf[j] = *(const bh8*)(Bs + (wn + j * 16 + (lane & 15)) * 128 + ks * 64 + (lane >> 4) * 16);
            #pragma unroll
            for (int i = 0; i < 4; ++i)
                #pragma unroll
                for (int j = 0; j < 4; ++j)
                    acc[i][j] = __builtin_amdgcn_mfma_f32_16x16x32_bf16(af[i], bf[j], acc[i][j], 0, 0, 0);
        }
    }

    bool isQ = (n0 < 256);
    int q4 = (lane >> 4) * 4;
    #pragma unroll
    for (int i = 0; i < 4; ++i) {
        #pragma unroll
        for (int j = 0; j < 4; ++j) {
            int ch = n0 + wn + j * 16 + (lane & 15);
            #pragma unroll
            for (int r = 0; r < 4; ++r) {
                int pix = m0 + wm + i * 16 + q4 + r;
                unsigned short v = f2bf(acc[i][j][r]);
                if (isQ) {
                    int head = ch >> 5, d = ch & 31;
                    qb[((size_t)(b * 8 + head) * NPIX + pix) * 32 + d] = v;
                } else {
                    int c = ch - 256, head = c >> 6, dv = c & 63;
                    kvb[((size_t)(b * 8 + head) * NPIX + pix) * 64 + dv] = v;
                }
            }
        }
    }
}

// ---------------------------------------------------------------------------
// Kernel 3: halo attention rewrite. kp = a*16 + b2 (224 padded slots).
// One block per (bh 64, nb 144), 4 waves; wave owns 16-qp strip.
// LDS map (50368 B -> 3 blocks/CU):
//   [0,15360)       Vt[32][240] bf16, granule-XOR swizzled   (all phases)
//   [15360,33280)   Ks[224][40] bf16                          (phase QK)
//   [33280,40896)   RhT[28][68] fp32 (wave-private rows)      (logits)
//   [40896,50112)   Rw[64][36]  fp32 (wave-private rows)      (logits)
//   [15360,45056)   Ps 4 x [16][232] bf16 (overlays Ks/RhT/Rw after S2)
//   [50112,50368)   smR[64] fp32 row-sums
// ---------------------------------------------------------------------------
__global__ __launch_bounds__(256) void attn_kernel(const unsigned short* __restrict__ qbuf,
                                                   const unsigned short* __restrict__ kvbuf,
                                                   const unsigned short* __restrict__ relb,
                                                   float* __restrict__ out) {
    int nbid = blockIdx.x, bh = blockIdx.y;
    int b = bh >> 3, head = bh & 7;
    int hb = nbid / 12, wblk = nbid % 12;
    int r0 = hb * 8, c0 = wblk * 8;
    int tid = threadIdx.x, lane = tid & 63, wave = tid >> 6;
    int ll = lane & 15, lq = lane >> 4;
    int m0 = wave * 16;

    __shared__ __align__(16) char smem[50368];
    unsigned short* Vt = (unsigned short*)smem;
    unsigned short* Ks = (unsigned short*)(smem + 15360);
    float*          RhT = (float*)(smem + 33280);
    float*          Rw  = (float*)(smem + 40896);
    unsigned short* Ps  = (unsigned short*)(smem + 15360 + wave * 7424);
    float*          smR = (float*)(smem + 50112);

    const unsigned short* qb  = qbuf  + (size_t)bh * NPIX * 32;
    const unsigned short* kvb = kvbuf + (size_t)bh * NPIX * 64;

    // ---- Q fragment straight from global (A-operand layout)
    int qp0 = m0 + ll;
    int pixq = (r0 + (qp0 >> 3)) * 96 + c0 + (qp0 & 7);
    bh8 aq = *(const bh8*)&qb[(size_t)pixq * 32 + lq * 8];

    // ---- stage K: 224 rows x 64 B, pad/halo-zeroed
    for (int e = tid; e < 896; e += 256) {
        int kp = e >> 2, part = e & 3;
        int a = kp >> 4, b2 = kp & 15;
        int gr = r0 + a - 3, gc = c0 + b2 - 3;
        int4 v = {0, 0, 0, 0};
        if (b2 < 14 && (unsigned)gr < 96u && (unsigned)gc < 96u)
            v = *(const int4*)&kvb[(size_t)(gr * 96 + gc) * 64 + part * 8];
        *(int4*)&Ks[kp * 40 + part * 8] = v;
    }

    // ---- stage V transposed: Vt[d][granule-swizzled kp], pair-packed b32
    #pragma unroll
    for (int it = 0; it < 2; ++it) {
        int e = it * 256 + tid;
        int part = e >> 7, kp2 = e & 127;
        if (kp2 < 112) {
            int a = kp2 >> 3, b2 = (kp2 & 7) * 2;
            int gr = r0 + a - 3, gc = c0 + b2 - 3;
            int4 lo = {0, 0, 0, 0}, hi = {0, 0, 0, 0};
            bool rok = ((kp2 & 7) < 7) && ((unsigned)gr < 96u);
            if (rok && (unsigned)gc < 96u)
                lo = *(const int4*)&kvb[(size_t)(gr * 96 + gc) * 64 + 32 + part * 8];
            if (rok && (unsigned)(gc + 1) < 96u)
                hi = *(const int4*)&kvb[(size_t)(gr * 96 + gc + 1) * 64 + 32 + part * 8];
            int g = kp2 >> 2, kb = b2 & 7;
            const unsigned* lw = (const unsigned*)&lo;
            const unsigned* hw = (const unsigned*)&hi;
            #pragma unroll
            for (int jw = 0; jw < 4; ++jw) {
                unsigned l2 = lw[jw], h2 = hw[jw];
                unsigned v0 = (l2 & 0xffffu) | (h2 << 16);
                unsigned v1 = (l2 >> 16) | (h2 & 0xffff0000u);
                int d0 = part * 8 + jw * 2;
                int s0 = (((jw * 2) & 3) + part) & 3;
                int s1 = (((jw * 2 + 1) & 3) + part) & 3;
                *(unsigned*)&Vt[d0 * 240 + ((g ^ s0) * 8) + kb] = v0;
                *(unsigned*)&Vt[(d0 + 1) * 240 + ((g ^ s1) * 8) + kb] = v1;
            }
        }
    }

    // ---- rel dot-products via MFMA (wave-private rows; relb pre-scaled LOG2E)
    f4 zero4 = {0.f, 0.f, 0.f, 0.f};
    #pragma unroll
    for (int t = 0; t < 2; ++t) {
        int r = t * 16 + ll;
        bh8 hbv = *(const bh8*)&relb[(size_t)r * 32 + lq * 8];
        bh8 wbv = *(const bh8*)&relb[1024 + (size_t)r * 32 + lq * 8];
        f4 ch = __builtin_amdgcn_mfma_f32_16x16x32_bf16(aq, hbv, zero4, 0, 0, 0);
        f4 cw = __builtin_amdgcn_mfma_f32_16x16x32_bf16(aq, wbv, zero4, 0, 0, 0);
        if (r < 28) *(f4*)&RhT[r * 68 + m0 + lq * 4] = ch;
        #pragma unroll
        for (int rr = 0; rr < 4; ++rr)
            Rw[(m0 + lq * 4 + rr) * 36 + r] = cw[rr];
    }

    __syncthreads();                               // S1: staging visible

    // ---- S = Q K^T (14 MFMAs)
    f4 S[14];
    #pragma unroll
    for (int t = 0; t < 14; ++t) {
        bh8 bk = *(const bh8*)&Ks[(t * 16 + ll) * 40 + lq * 8];
        S[t] = __builtin_amdgcn_mfma_f32_16x16x32_bf16(aq, bk, zero4, 0, 0, 0);
    }

    // ---- logits (log2 domain), exp2 without max-subtraction, row sums
    int row0 = m0 + lq * 4;
    int h = row0 >> 3;                             // quad-uniform
    float rw4[4];
    #pragma unroll
    for (int rr = 0; rr < 4; ++rr) {
        int row = row0 + rr;
        rw4[rr] = Rw[row * 36 + 13 + ll - (row & 7)];
    }
    const float SL = SCALE * LOG2E;
    bool valid = ll < 14;
    float sm4[4] = {0.f, 0.f, 0.f, 0.f};
    #pragma unroll
    for (int t = 0; t < 14; ++t) {
        f4 rh = *(const f4*)&RhT[(13 + t - h) * 68 + row0];
        #pragma unroll
        for (int rr = 0; rr < 4; ++rr) {
            float lg = S[t][rr] * SL + rh[rr] + rw4[rr];
            float p = valid ? __builtin_amdgcn_exp2f(lg) : 0.0f;
            S[t][rr] = p;
            sm4[rr] += p;
        }
    }
    #pragma unroll
    for (int rr = 0; rr < 4; ++rr) {
        sm4[rr] += __shfl_xor(sm4[rr], 1);
        sm4[rr] += __shfl_xor(sm4[rr], 2);
        sm4[rr] += __shfl_xor(sm4[rr], 4);
        sm4[rr] += __shfl_xor(sm4[rr], 8);
    }
    if (ll == 0) {
        #pragma unroll
        for (int rr = 0; rr < 4; ++rr) smR[row0 + rr] = sm4[rr];
    }

    __syncthreads();                               // S2: Ks/RhT/Rw dead

    // ---- P -> LDS row-major (wave-private strip), B-operand-readable
    #pragma unroll
    for (int t = 0; t < 14; ++t) {
        int col = t * 16 + ll;
        #pragma unroll
        for (int rr = 0; rr < 4; ++rr)
            Ps[(lq * 4 + rr) * 232 + col] = f2bf(S[t][rr]);
    }

    // ---- O^T = V^T P^T: A = Vt (b128), B = Ps (b128), 14 MFMAs
    f4 O[2] = {zero4, zero4};
    #pragma unroll
    for (int kt = 0; kt < 7; ++kt) {
        bh8 bp = *(const bh8*)&Ps[ll * 232 + kt * 32 + lq * 8];
        #pragma unroll
        for (int mt = 0; mt < 2; ++mt) {
            int d = mt * 16 + ll;
            int s = ((d & 3) + ((d >> 3) & 3)) & 3;
            bh8 av = *(const bh8*)&Vt[d * 240 + (((kt * 4 + lq) ^ s) * 8)];
            O[mt] = __builtin_amdgcn_mfma_f32_16x16x32_bf16(av, bp, O[mt], 0, 0, 0);
        }
    }

    // ---- epilogue: O^T lanes are pixel-consecutive -> coalesced-8 stores
    int qp = m0 + ll;
    float rs = 1.0f / smR[qp];
    int pix = (r0 + (qp >> 3)) * 96 + c0 + (qp & 7);
    float* ob = out + (size_t)(b * 256 + head * 32) * NPIX;
    #pragma unroll
    for (int mt = 0; mt < 2; ++mt) {
        #pragma unroll
        for (int rr = 0; rr < 4; ++rr) {
            int d = mt * 16 + lq * 4 + rr;
            ob[(size_t)d * NPIX + pix] = O[mt][rr] * rs;
        }
    }
}

extern "C" void kernel_launch(void* const* d_in, const int* in_sizes, int n_in,
                              void* d_out, int out_size, void* d_ws, size_t ws_size,
                              hipStream_t stream) {
    const float* x    = (const float*)d_in[0];
    const float* qw   = (const float*)d_in[1];
    const float* kvw  = (const float*)d_in[2];
    const float* hrel = (const float*)d_in[3];
    const float* wrel = (const float*)d_in[4];
    float* out = (float*)d_out;

    char* ws = (char*)d_ws;
    unsigned short* xt    = (unsigned short*)ws;                 // 37,748,736 B
    unsigned short* Wb    = (unsigned short*)(ws + 37748736);    //    393,216 B
    unsigned short* relb  = (unsigned short*)(ws + 38141952);    //      4,096 B
    unsigned short* qbuf  = (unsigned short*)(ws + 38146048);    // 37,748,736 B
    unsigned short* kvbuf = (unsigned short*)(ws + 75894784);    // 75,497,472 B

    wconv_kernel<<<dim3(776), 256, 0, stream>>>(qw, kvw, hrel, wrel, Wb, relb);
    xtrans_kernel<<<dim3(72, 2, 8), 256, 0, stream>>>(x, xt);
    proj_kernel<<<dim3(72, 6, 8), 256, 0, stream>>>(xt, Wb, qbuf, kvbuf);
    attn_kernel<<<dim3(144, 64), 256, 0, stream>>>(qbuf, kvbuf, relb, out);
}